// Round 9
// baseline (34.796 us; speedup 1.0000x reference)
//
#include <hip/hip_runtime.h>

#define INDIM  128
#define OUTDIM 128
#define GSZ    5
#define BATCH  1024
#define KTOT   1152      // 128 in * 8 w-slots + 128 silu slots
#define APAD   1160      // pad -> 2320B row stride
#define NYB    64        // y-role blocks (16b x 128o each)
#define NRB    512       // REG-role blocks (in x 32-o slice)

typedef _Float16 half_t;
typedef _Float16 half8 __attribute__((ext_vector_type(8)));
typedef float    f32x4 __attribute__((ext_vector_type(4)));

// 8 weight-slot basis values for one x (uniform cubic B-spline, reference knots)
__device__ __forceinline__ half8 basis8(float x, float g0, float g5) {
    const float h  = (g5 - g0) * (1.0f / GSZ);
    const float e0 = ((g0 - h) - h) - h;       // matches reference sequential knot build
    const float xb = (x - e0) * (1.0f / h);
    const float jf = floorf(xb);
    const int   j0 = (int)jf;
    const float u  = xb - jf;
    const float t1 = 1.0f - u;
    const float u2 = u * u, u3 = u2 * u;
    const float c0 = t1 * t1 * t1 * (1.0f / 6.0f);
    const float c1 = fmaf(0.5f, u3, fmaf(-1.0f, u2, 2.0f / 3.0f));
    const float c2 = fmaf(-0.5f, u3, fmaf(0.5f, u2, fmaf(0.5f, u, 1.0f / 6.0f)));
    const float c3 = u3 * (1.0f / 6.0f);
    half8 bs = {0, 0, 0, 0, 0, 0, 0, 0};
#pragma unroll
    for (int k = 0; k < 8; ++k) {
        const int d = k - j0 + 3;              // outside weight range -> 0 (ref truncation)
        const float v = (d == 0) ? c0 : (d == 1) ? c1 : (d == 2) ? c2 : (d == 3) ? c3 : 0.0f;
        bs[k] = (half_t)v;
    }
    return bs;
}

__device__ __forceinline__ half8 cvt8(float4 a, float4 b, float s) {
    half8 r;
    r[0] = (half_t)(s * a.x); r[1] = (half_t)(s * a.y);
    r[2] = (half_t)(s * a.z); r[3] = (half_t)(s * a.w);
    r[4] = (half_t)(s * b.x); r[5] = (half_t)(s * b.y);
    r[6] = (half_t)(s * b.z); r[7] = (half_t)(s * b.w);
    return r;
}

// 512 threads / block (8 waves).
// bid <  NYB : y-block — 16 batches x all 128 o (wave w -> o-tile w)
// bid >= NYB : REG-block — (in, 32-o slice); waves: (w&1)=o-tile, (w>>1)=b-split
__global__ __launch_bounds__(512, 2) void k_fused(
    const float* __restrict__ X, const float* __restrict__ G,
    const float* __restrict__ W, const float* __restrict__ Csp,
    const float* __restrict__ Cre,
    float* __restrict__ Y, float* __restrict__ REG)
{
    __shared__ __align__(16) unsigned char smem[16 * APAD * 2];   // 37120 B (role-max)
    const int bid = blockIdx.x, t = threadIdx.x;
    const int w = t >> 6, lane = t & 63;
    const int col = lane & 15, quad = lane >> 4;
    const f32x4 zero4 = {0.f, 0.f, 0.f, 0.f};

    if (bid < NYB) {
        // ---------------- y: 16m x 128n tile, 8 waves = 8 n-tiles ----------------
        half_t (*A)[APAD] = (half_t (*)[APAD])smem;
        const int m0 = bid * 16;
        const int in = t & 127;
        const float g0 = G[in * 6 + 0], g5 = G[in * 6 + 5];
        for (int r = t >> 7; r < 16; r += 4) {
            const float x = X[(m0 + r) * INDIM + in];
            *(half8*)&A[r][in * 8] = basis8(x, g0, g5);
            A[r][1024 + in] = (half_t)(x / (1.0f + __expf(-x)));
        }
        __syncthreads();

        const int o = w * 16 + col;
        f32x4 acc = zero4;
#pragma unroll 6
        for (int kt = 0; kt < 36; ++kt) {
            const half8 a = *(const half8*)&A[col][kt * 32 + quad * 8];
            half8 bfrag;
            if (kt < 32) {
                const int s = o * INDIM + (kt * 4 + quad);   // in' covered by this k-slot
                const float4 w0 = *(const float4*)&W[s * 8];
                const float4 w1 = *(const float4*)&W[s * 8 + 4];
                bfrag = cvt8(w0, w1, Csp[s]);                // csp * W
            } else {
                const int i0 = (kt - 32) * 32 + quad * 8;
                const float4 c0 = *(const float4*)&Cre[o * INDIM + i0];
                const float4 c1 = *(const float4*)&Cre[o * INDIM + i0 + 4];
                bfrag = cvt8(c0, c1, 1.0f);                  // cre (silu slots)
            }
            acc = __builtin_amdgcn_mfma_f32_16x16x32_f16(a, bfrag, acc, 0, 0, 0);
        }
#pragma unroll
        for (int r = 0; r < 4; ++r)
            Y[(m0 + quad * 4 + r) * OUTDIM + o] = acc[r] * (1.0f / INDIM);
    } else {
        // ---------------- REG: one in, 32 o's, |spl| reduced over all b ----------------
        half_t (*Bb)[8] = (half_t (*)[8])smem;               // [1024][8], 16 KB
        float* SH = (float*)(smem + BATCH * 8 * sizeof(half_t));  // [8][16]
        const int rb = bid - NYB;
        const int in = rb & 127;
        const int o0 = (rb >> 7) * 32;
        const float g0 = G[in * 6 + 0], g5 = G[in * 6 + 5];
        for (int b = t; b < BATCH; b += 512)
            *(half8*)&Bb[b][0] = basis8(X[b * INDIM + in], g0, g5);
        __syncthreads();

        const int ot = w & 1;                  // o-tile within the 32-o slice
        const int bs = w >> 1;                 // 4-way b split
        // real k=0..7 live in quad==0 lanes of BOTH A and B (k-map cancels)
        half8 bfrag = {0, 0, 0, 0, 0, 0, 0, 0};
        if (quad == 0) {
            const int s = (o0 + ot * 16 + col) * INDIM + in;
            const float4 w0 = *(const float4*)&W[s * 8];
            const float4 w1 = *(const float4*)&W[s * 8 + 4];
            bfrag = cvt8(w0, w1, 1.0f);                      // raw W
        }
        float r0 = 0.f, r1 = 0.f, r2 = 0.f, r3 = 0.f;
#pragma unroll 4
        for (int bt = bs; bt < 64; bt += 4) {                // waves split the b-tiles
            half8 a = {0, 0, 0, 0, 0, 0, 0, 0};
            if (quad == 0)
                a = *(const half8*)&Bb[bt * 16 + col][0];
            const f32x4 c = __builtin_amdgcn_mfma_f32_16x16x32_f16(a, bfrag, zero4, 0, 0, 0);
            r0 += fabsf(c[0]); r1 += fabsf(c[1]); r2 += fabsf(c[2]); r3 += fabsf(c[3]);
        }
        float sum = (r0 + r1) + (r2 + r3);
        sum += __shfl_xor(sum, 16);
        sum += __shfl_xor(sum, 32);
        if (lane < 16) SH[w * 16 + lane] = sum;              // per-wave partials
        __syncthreads();
        if (t < 32) {
            const int ot2 = t >> 4, l = t & 15;
            const int o = o0 + ot2 * 16 + l;
            const int s = o * INDIM + in;
            const float gg0 = G[s * 6], gg5 = G[s * 6 + 5];
            const float tot = SH[(ot2 + 0) * 16 + l] + SH[(ot2 + 2) * 16 + l]
                            + SH[(ot2 + 4) * 16 + l] + SH[(ot2 + 6) * 16 + l];
            REG[s] = tot * (1.0f / BATCH) / (gg5 - gg0 + 1e-5f);
        }
    }
}

extern "C" void kernel_launch(void* const* d_in, const int* in_sizes, int n_in,
                              void* d_out, int out_size, void* d_ws, size_t ws_size,
                              hipStream_t stream) {
    const float* X   = (const float*)d_in[0];
    const float* G   = (const float*)d_in[1];
    const float* W   = (const float*)d_in[2];
    const float* Csp = (const float*)d_in[3];
    const float* Cre = (const float*)d_in[4];
    float* Y   = (float*)d_out;                    // (1024,128) unique-owner stores
    float* REG = (float*)d_out + BATCH * OUTDIM;   // (128,128)  unique-owner stores

    k_fused<<<NYB + NRB, 512, 0, stream>>>(X, G, W, Csp, Cre, Y, REG);
}

// Round 11
// 25.521 us; speedup vs baseline: 1.3634x; 1.3634x over previous
//
#include <hip/hip_runtime.h>

#define INDIM  128
#define OUTDIM 128
#define GSZ    5
#define BATCH  1024
#define KTOT   1152      // 128 in * 8 w-slots + 128 silu slots
#define APAD   1160

typedef _Float16 half_t;
typedef _Float16 half8 __attribute__((ext_vector_type(8)));
typedef float    f32x4 __attribute__((ext_vector_type(4)));

// ws layout (half_t units):
//  Bh  [1024][1152] : [b][in*8+k] basis, [b][1024+in] silu   (y-role A)
//  Bh2 [128][1024*8]: [in][b*8+k] basis                      (REG-role A)
//  Wc  [128][1152]  : [o][in*8+k] csp*W, [o][1024+in] cre    (y-role B)
//  Wr  [128][128*8] : [in][o*8+k] raw W                      (REG-role B)
#define BH2_OFF  (BATCH * KTOT)                    // 1179648
#define WC_OFF   (BH2_OFF + INDIM * BATCH * 8)     // 2228224
#define WR_OFF   (WC_OFF + OUTDIM * KTOT)          // 2375680

// 8 weight-slot basis values for one x (uniform cubic B-spline, reference knots)
__device__ __forceinline__ half8 basis8(float x, float g0, float g5) {
    const float h  = (g5 - g0) * (1.0f / GSZ);
    const float e0 = ((g0 - h) - h) - h;       // matches reference sequential knot build
    const float xb = (x - e0) * (1.0f / h);
    const float jf = floorf(xb);
    const int   j0 = (int)jf;
    const float u  = xb - jf;
    const float t1 = 1.0f - u;
    const float u2 = u * u, u3 = u2 * u;
    const float c0 = t1 * t1 * t1 * (1.0f / 6.0f);
    const float c1 = fmaf(0.5f, u3, fmaf(-1.0f, u2, 2.0f / 3.0f));
    const float c2 = fmaf(-0.5f, u3, fmaf(0.5f, u2, fmaf(0.5f, u, 1.0f / 6.0f)));
    const float c3 = u3 * (1.0f / 6.0f);
    half8 bs = {0, 0, 0, 0, 0, 0, 0, 0};
#pragma unroll
    for (int k = 0; k < 8; ++k) {
        const int d = k - j0 + 3;              // outside weight range -> 0 (ref truncation)
        const float v = (d == 0) ? c0 : (d == 1) ? c1 : (d == 2) ? c2 : (d == 3) ? c3 : 0.0f;
        bs[k] = (half_t)v;
    }
    return bs;
}

__device__ __forceinline__ half8 cvt8(float4 a, float4 b, float s) {
    half8 r;
    r[0] = (half_t)(s * a.x); r[1] = (half_t)(s * a.y);
    r[2] = (half_t)(s * a.z); r[3] = (half_t)(s * a.w);
    r[4] = (half_t)(s * b.x); r[5] = (half_t)(s * b.y);
    r[6] = (half_t)(s * b.z); r[7] = (half_t)(s * b.w);
    return r;
}

// ---------------- phase 1: dedup'd basis + weight prep ----------------
// grid = 512 basis-blocks (131072 (b,in) evals) + 64 weight-blocks (16384 s)
__global__ __launch_bounds__(256) void k_prep(
    const float* __restrict__ X, const float* __restrict__ G,
    const float* __restrict__ W, const float* __restrict__ Csp,
    const float* __restrict__ Cre, half_t* __restrict__ ws)
{
    const int bid = blockIdx.x, t = threadIdx.x;
    if (bid < 512) {
        const int gid = bid * 256 + t;         // b*128 + in, coalesced X read
        const int b = gid >> 7, in = gid & 127;
        const float x  = X[gid];
        const float g0 = G[in * 6 + 0], g5 = G[in * 6 + 5];   // grid identical across o
        const half8 bs = basis8(x, g0, g5);
        *(half8*)&ws[b * KTOT + in * 8] = bs;                 // coalesced
        ws[b * KTOT + 1024 + in] = (half_t)(x / (1.0f + __expf(-x)));
        *(half8*)&ws[BH2_OFF + in * (BATCH * 8) + b * 8] = bs; // scattered write (no stall)
    } else {
        const int s = (bid - 512) * 256 + t;   // o*128 + in, coalesced; s < 16384
        const int o = s >> 7, in = s & 127;
        const float4 w0 = *(const float4*)&W[s * 8];
        const float4 w1 = *(const float4*)&W[s * 8 + 4];
        *(half8*)&ws[WC_OFF + o * KTOT + in * 8] = cvt8(w0, w1, Csp[s]);
        ws[WC_OFF + o * KTOT + 1024 + in] = (half_t)Cre[s];
        *(half8*)&ws[WR_OFF + in * (OUTDIM * 8) + o * 8] = cvt8(w0, w1, 1.0f);
    }
}

// ---------------- phase 2a: REG — 1024 blocks (in, 16-o), tiny LDS ----------------
__global__ __launch_bounds__(256) void k_reg(
    const float* __restrict__ G, const half_t* __restrict__ ws,
    float* __restrict__ REG)
{
    __shared__ float SH[64];
    const int t = threadIdx.x, w = t >> 6, lane = t & 63;
    const int col = lane & 15, quad = lane >> 4;
    const int in = blockIdx.x & 127;
    const int o0 = (blockIdx.x >> 7) * 16;
    const f32x4 zero4 = {0.f, 0.f, 0.f, 0.f};

    // real k=0..7 live in quad==0 slots of BOTH A and B (k-map cancels)
    half8 bfrag = {0, 0, 0, 0, 0, 0, 0, 0};
    if (quad == 0)
        bfrag = *(const half8*)&ws[WR_OFF + in * (OUTDIM * 8) + (o0 + col) * 8];
    float r0 = 0.f, r1 = 0.f, r2 = 0.f, r3 = 0.f;
#pragma unroll 4
    for (int bt = w; bt < 64; bt += 4) {       // 4 waves split the 64 b-tiles
        half8 a = {0, 0, 0, 0, 0, 0, 0, 0};
        if (quad == 0)
            a = *(const half8*)&ws[BH2_OFF + in * (BATCH * 8) + (bt * 16 + col) * 8];
        const f32x4 c = __builtin_amdgcn_mfma_f32_16x16x32_f16(a, bfrag, zero4, 0, 0, 0);
        r0 += fabsf(c[0]); r1 += fabsf(c[1]); r2 += fabsf(c[2]); r3 += fabsf(c[3]);
    }
    float sum = (r0 + r1) + (r2 + r3);
    sum += __shfl_xor(sum, 16);
    sum += __shfl_xor(sum, 32);
    if (lane < 16) SH[w * 16 + lane] = sum;
    __syncthreads();
    if (t < 16) {
        const int s = (o0 + t) * INDIM + in;
        const float gg0 = G[s * 6], gg5 = G[s * 6 + 5];
        REG[s] = (SH[t] + SH[16 + t] + SH[32 + t] + SH[48 + t])
                 * (1.0f / BATCH) / (gg5 - gg0 + 1e-5f);
    }
}

// ---------------- phase 2b: y — 128 blocks (16b x 64o), LDS A-panel ----------------
__global__ __launch_bounds__(256) void k_y(
    const half_t* __restrict__ ws, float* __restrict__ Y)
{
    __shared__ __align__(16) half_t A[16][APAD];
    const int t = threadIdx.x, w = t >> 6, lane = t & 63;
    const int col = lane & 15, quad = lane >> 4;
    const int m0 = (blockIdx.x >> 1) * 16;
    const int nh = blockIdx.x & 1;
    const f32x4 zero4 = {0.f, 0.f, 0.f, 0.f};

    // stage A-panel: 16 rows x 1152 halfs, 16B per thread per iter, coalesced
#pragma unroll
    for (int idx = t; idx < 16 * 144; idx += 256) {
        const int r = idx / 144, c = idx % 144;
        *(half8*)&A[r][c * 8] = *(const half8*)&ws[(m0 + r) * KTOT + c * 8];
    }
    __syncthreads();

    const int o = nh * 64 + w * 16 + col;
    f32x4 acc = zero4;
#pragma unroll 6
    for (int kt = 0; kt < 36; ++kt) {
        const half8 a = *(const half8*)&A[col][kt * 32 + quad * 8];
        const half8 b = *(const half8*)&ws[WC_OFF + o * KTOT + kt * 32 + quad * 8];
        acc = __builtin_amdgcn_mfma_f32_16x16x32_f16(a, b, acc, 0, 0, 0);
    }
#pragma unroll
    for (int r = 0; r < 4; ++r)
        Y[(m0 + quad * 4 + r) * OUTDIM + o] = acc[r] * (1.0f / INDIM);
}

extern "C" void kernel_launch(void* const* d_in, const int* in_sizes, int n_in,
                              void* d_out, int out_size, void* d_ws, size_t ws_size,
                              hipStream_t stream) {
    const float* X   = (const float*)d_in[0];
    const float* G   = (const float*)d_in[1];
    const float* W   = (const float*)d_in[2];
    const float* Csp = (const float*)d_in[3];
    const float* Cre = (const float*)d_in[4];
    float* Y   = (float*)d_out;                    // (1024,128) unique-owner stores
    float* REG = (float*)d_out + BATCH * OUTDIM;   // (128,128)  unique-owner stores
    half_t* ws = (half_t*)d_ws;

    k_prep<<<576, 256, 0, stream>>>(X, G, W, Csp, Cre, ws);
    k_reg<<<1024, 256, 0, stream>>>(G, ws, REG);
    k_y<<<128, 256, 0, stream>>>(ws, Y);
}

// Round 12
// 21.000 us; speedup vs baseline: 1.6569x; 1.2153x over previous
//
#include <hip/hip_runtime.h>

#define INDIM  128
#define OUTDIM 128
#define GSZ    5
#define BATCH  1024
#define KTOT   1152      // 128 in * 8 w-slots + 128 silu slots
#define APAD   1160

typedef _Float16 half_t;
typedef _Float16 half8 __attribute__((ext_vector_type(8)));
typedef float    f32x4 __attribute__((ext_vector_type(4)));

// ws layout (half_t units):
//  Bh  [1024][1152] : [b][in*8+k] basis, [b][1024+in] silu   (y-role A)
//  Bh2 [128][1024*8]: [in][b*8+k] basis                      (REG-role A)
//  Wc  [128][1152]  : [o][in*8+k] csp*W, [o][1024+in] cre    (y-role B)
// Every region is written with single-warp-owned, coalesced 128B lines.
#define BH2_OFF  (BATCH * KTOT)                    // 1179648
#define WC_OFF   (BH2_OFF + INDIM * BATCH * 8)     // 2228224

// 8 weight-slot basis values for one x (uniform cubic B-spline, reference knots)
__device__ __forceinline__ half8 basis8(float x, float g0, float g5) {
    const float h  = (g5 - g0) * (1.0f / GSZ);
    const float e0 = ((g0 - h) - h) - h;       // matches reference sequential knot build
    const float xb = (x - e0) * (1.0f / h);
    const float jf = floorf(xb);
    const int   j0 = (int)jf;
    const float u  = xb - jf;
    const float t1 = 1.0f - u;
    const float u2 = u * u, u3 = u2 * u;
    const float c0 = t1 * t1 * t1 * (1.0f / 6.0f);
    const float c1 = fmaf(0.5f, u3, fmaf(-1.0f, u2, 2.0f / 3.0f));
    const float c2 = fmaf(-0.5f, u3, fmaf(0.5f, u2, fmaf(0.5f, u, 1.0f / 6.0f)));
    const float c3 = u3 * (1.0f / 6.0f);
    half8 bs = {0, 0, 0, 0, 0, 0, 0, 0};
#pragma unroll
    for (int k = 0; k < 8; ++k) {
        const int d = k - j0 + 3;              // outside weight range -> 0 (ref truncation)
        const float v = (d == 0) ? c0 : (d == 1) ? c1 : (d == 2) ? c2 : (d == 3) ? c3 : 0.0f;
        bs[k] = (half_t)v;
    }
    return bs;
}

__device__ __forceinline__ half8 cvt8(float4 a, float4 b, float s) {
    half8 r;
    r[0] = (half_t)(s * a.x); r[1] = (half_t)(s * a.y);
    r[2] = (half_t)(s * a.z); r[3] = (half_t)(s * a.w);
    r[4] = (half_t)(s * b.x); r[5] = (half_t)(s * b.y);
    r[6] = (half_t)(s * b.z); r[7] = (half_t)(s * b.w);
    return r;
}

// ---------------- D1: prep. 1088 blocks, every ws line single-warp-owned ----------------
__global__ __launch_bounds__(256) void k_prep(
    const float* __restrict__ X, const float* __restrict__ G,
    const float* __restrict__ W, const float* __restrict__ Csp,
    const float* __restrict__ Cre, half_t* __restrict__ ws)
{
    const int bid = blockIdx.x, t = threadIdx.x;
    if (bid < 512) {
        // in-major: write Bh2 coalesced (b varies per lane); X read scattered (read-only)
        const int in = bid >> 2;
        const int b  = ((bid & 3) << 8) + t;
        const float g0 = G[in * 6 + 0], g5 = G[in * 6 + 5];
        const half8 bs = basis8(X[b * INDIM + in], g0, g5);
        *(half8*)&ws[BH2_OFF + in * (BATCH * 8) + b * 8] = bs;
    } else if (bid < 1024) {
        // b-major: write Bh + silu coalesced (in varies per lane); X read coalesced
        const int gid = (bid - 512) * 256 + t;
        const int b = gid >> 7, in = gid & 127;
        const float x  = X[gid];
        const float g0 = G[in * 6 + 0], g5 = G[in * 6 + 5];
        *(half8*)&ws[b * KTOT + in * 8] = basis8(x, g0, g5);
        ws[b * KTOT + 1024 + in] = (half_t)(x / (1.0f + __expf(-x)));
    } else {
        // weights: Wc row-coalesced (in varies per lane)
        const int s = (bid - 1024) * 256 + t;  // o*128 + in, s < 16384
        const int o = s >> 7, in = s & 127;
        const float4 w0 = *(const float4*)&W[s * 8];
        const float4 w1 = *(const float4*)&W[s * 8 + 4];
        *(half8*)&ws[WC_OFF + o * KTOT + in * 8] = cvt8(w0, w1, Csp[s]);
        ws[WC_OFF + o * KTOT + 1024 + in] = (half_t)Cre[s];
    }
}

// ---------------- D2: y (bid<128, launched first) + REG (1024 blocks) ----------------
__global__ __launch_bounds__(256) void k_main(
    const float* __restrict__ G, const float* __restrict__ W,
    const half_t* __restrict__ ws,
    float* __restrict__ Y, float* __restrict__ REG)
{
    __shared__ __align__(16) unsigned char smem[16 * APAD * 2];   // 37120 B
    const int bid = blockIdx.x, t = threadIdx.x;
    const int w = t >> 6, lane = t & 63;
    const int col = lane & 15, quad = lane >> 4;
    const f32x4 zero4 = {0.f, 0.f, 0.f, 0.f};

    if (bid < 128) {
        // ---- y role: 16b x 64o tile; REG-blocks provide TLP cover ----
        half_t (*A)[APAD] = (half_t (*)[APAD])smem;
        const int m0 = (bid >> 1) * 16;
        const int nh = bid & 1;
#pragma unroll
        for (int idx = t; idx < 16 * 144; idx += 256) {
            const int r = idx / 144, c = idx % 144;
            *(half8*)&A[r][c * 8] = *(const half8*)&ws[(m0 + r) * KTOT + c * 8];
        }
        __syncthreads();

        const int o = nh * 64 + w * 16 + col;
        f32x4 acc = zero4;
#pragma unroll 6
        for (int kt = 0; kt < 36; ++kt) {
            const half8 a = *(const half8*)&A[col][kt * 32 + quad * 8];
            const half8 b = *(const half8*)&ws[WC_OFF + o * KTOT + kt * 32 + quad * 8];
            acc = __builtin_amdgcn_mfma_f32_16x16x32_f16(a, b, acc, 0, 0, 0);
        }
#pragma unroll
        for (int r = 0; r < 4; ++r)
            Y[(m0 + quad * 4 + r) * OUTDIM + o] = acc[r] * (1.0f / INDIM);
    } else {
        // ---- REG role: (in, 16-o slice), |spl| over all b ----
        float* SH = (float*)smem;
        const int rb = bid - 128;
        const int in = rb & 127;
        const int o0 = (rb >> 7) * 16;

        // raw W fragment, converted in-kernel (Wr region eliminated)
        half8 bfrag = {0, 0, 0, 0, 0, 0, 0, 0};
        if (quad == 0) {
            const int s = (o0 + col) * INDIM + in;
            const float4 w0 = *(const float4*)&W[s * 8];
            const float4 w1 = *(const float4*)&W[s * 8 + 4];
            bfrag = cvt8(w0, w1, 1.0f);
        }
        float r0 = 0.f, r1 = 0.f, r2 = 0.f, r3 = 0.f;
#pragma unroll 4
        for (int bt = w; bt < 64; bt += 4) {   // 4 waves split the 64 b-tiles
            half8 a = {0, 0, 0, 0, 0, 0, 0, 0};
            if (quad == 0)
                a = *(const half8*)&ws[BH2_OFF + in * (BATCH * 8) + (bt * 16 + col) * 8];
            const f32x4 c = __builtin_amdgcn_mfma_f32_16x16x32_f16(a, bfrag, zero4, 0, 0, 0);
            r0 += fabsf(c[0]); r1 += fabsf(c[1]); r2 += fabsf(c[2]); r3 += fabsf(c[3]);
        }
        float sum = (r0 + r1) + (r2 + r3);
        sum += __shfl_xor(sum, 16);
        sum += __shfl_xor(sum, 32);
        if (lane < 16) SH[w * 16 + lane] = sum;
        __syncthreads();
        if (t < 16) {
            const int s = (o0 + t) * INDIM + in;
            const float gg0 = G[s * 6], gg5 = G[s * 6 + 5];
            REG[s] = (SH[t] + SH[16 + t] + SH[32 + t] + SH[48 + t])
                     * (1.0f / BATCH) / (gg5 - gg0 + 1e-5f);
        }
    }
}

extern "C" void kernel_launch(void* const* d_in, const int* in_sizes, int n_in,
                              void* d_out, int out_size, void* d_ws, size_t ws_size,
                              hipStream_t stream) {
    const float* X   = (const float*)d_in[0];
    const float* G   = (const float*)d_in[1];
    const float* W   = (const float*)d_in[2];
    const float* Csp = (const float*)d_in[3];
    const float* Cre = (const float*)d_in[4];
    float* Y   = (float*)d_out;                    // (1024,128) unique-owner stores
    float* REG = (float*)d_out + BATCH * OUTDIM;   // (128,128)  unique-owner stores
    half_t* ws = (half_t*)d_ws;

    k_prep<<<1088, 256, 0, stream>>>(X, G, W, Csp, Cre, ws);
    k_main<<<1152, 256, 0, stream>>>(G, W, ws, Y, REG);
}

// Round 13
// 20.890 us; speedup vs baseline: 1.6657x; 1.0053x over previous
//
#include <hip/hip_runtime.h>

#define INDIM  128
#define OUTDIM 128
#define GSZ    5
#define BATCH  1024
#define KTOT   1152      // 128 in * 8 w-slots + 128 silu slots
#define APAD   1160

typedef _Float16 half_t;
typedef _Float16 half8 __attribute__((ext_vector_type(8)));
typedef float    f32x4 __attribute__((ext_vector_type(4)));

// ws layout (half_t units):
//  Bh  [1024][1152]  : [b][in*8+k] basis, [b][1024+in] silu   (y-role A)
//  Bh2 [128][1024*8] : [in][b*8+k] basis                      (REG-role A)
//  Wc2 [144][128][8] : [kc][o][j] K-chunk-major B-operand:
//                      kc<128: csp*W (kc=in); kc>=128: cre at [128+in/8][o][in%8]
// Every region written with single-block-owned, coalesced lines.
#define BH2_OFF  (BATCH * KTOT)                    // 1179648
#define WC_OFF   (BH2_OFF + INDIM * BATCH * 8)     // 2228224

// 8 weight-slot basis values for one x (uniform cubic B-spline, reference knots)
__device__ __forceinline__ half8 basis8(float x, float g0, float g5) {
    const float h  = (g5 - g0) * (1.0f / GSZ);
    const float e0 = ((g0 - h) - h) - h;       // matches reference sequential knot build
    const float xb = (x - e0) * (1.0f / h);
    const float jf = floorf(xb);
    const int   j0 = (int)jf;
    const float u  = xb - jf;
    const float t1 = 1.0f - u;
    const float u2 = u * u, u3 = u2 * u;
    const float c0 = t1 * t1 * t1 * (1.0f / 6.0f);
    const float c1 = fmaf(0.5f, u3, fmaf(-1.0f, u2, 2.0f / 3.0f));
    const float c2 = fmaf(-0.5f, u3, fmaf(0.5f, u2, fmaf(0.5f, u, 1.0f / 6.0f)));
    const float c3 = u3 * (1.0f / 6.0f);
    half8 bs = {0, 0, 0, 0, 0, 0, 0, 0};
#pragma unroll
    for (int k = 0; k < 8; ++k) {
        const int d = k - j0 + 3;              // outside weight range -> 0 (ref truncation)
        const float v = (d == 0) ? c0 : (d == 1) ? c1 : (d == 2) ? c2 : (d == 3) ? c3 : 0.0f;
        bs[k] = (half_t)v;
    }
    return bs;
}

__device__ __forceinline__ half8 cvt8(float4 a, float4 b, float s) {
    half8 r;
    r[0] = (half_t)(s * a.x); r[1] = (half_t)(s * a.y);
    r[2] = (half_t)(s * a.z); r[3] = (half_t)(s * a.w);
    r[4] = (half_t)(s * b.x); r[5] = (half_t)(s * b.y);
    r[6] = (half_t)(s * b.z); r[7] = (half_t)(s * b.w);
    return r;
}

// ---------------- D1: prep. 1088 blocks, every ws line single-block-owned ----------------
__global__ __launch_bounds__(256) void k_prep(
    const float* __restrict__ X, const float* __restrict__ G,
    const float* __restrict__ W, const float* __restrict__ Csp,
    const float* __restrict__ Cre, half_t* __restrict__ ws)
{
    const int bid = blockIdx.x, t = threadIdx.x;
    if (bid < 512) {
        // in-major: write Bh2 coalesced (b varies per lane); X read gathered (read-only)
        const int in = bid >> 2;
        const int b  = ((bid & 3) << 8) + t;
        const float g0 = G[in * 6 + 0], g5 = G[in * 6 + 5];
        const half8 bs = basis8(X[b * INDIM + in], g0, g5);
        *(half8*)&ws[BH2_OFF + in * (BATCH * 8) + b * 8] = bs;
    } else if (bid < 1024) {
        // b-major: write Bh + silu coalesced (in varies per lane); X read coalesced
        const int gid = (bid - 512) * 256 + t;
        const int b = gid >> 7, in = gid & 127;
        const float x  = X[gid];
        const float g0 = G[in * 6 + 0], g5 = G[in * 6 + 5];
        *(half8*)&ws[b * KTOT + in * 8] = basis8(x, g0, g5);
        ws[b * KTOT + 1024 + in] = (half_t)(x / (1.0f + __expf(-x)));
    } else {
        // weights, in-major: Wc2 writes coalesced per in-row; W/Csp/Cre gathers read-only
        const int sp = (bid - 1024) * 256 + t;   // in*128 + o
        const int in = sp >> 7, o = sp & 127;
        const int s  = o * INDIM + in;           // original edge index
        const float4 w0 = *(const float4*)&W[s * 8];
        const float4 w1 = *(const float4*)&W[s * 8 + 4];
        *(half8*)&ws[WC_OFF + (in * 128 + o) * 8] = cvt8(w0, w1, Csp[s]);
        ws[WC_OFF + ((128 + (in >> 3)) * 128 + o) * 8 + (in & 7)] = (half_t)Cre[s];
    }
}

// ---------------- D2: y (bid<128) + REG (1024 blocks) ----------------
__global__ __launch_bounds__(256) void k_main(
    const float* __restrict__ G, const float* __restrict__ W,
    const half_t* __restrict__ ws,
    float* __restrict__ Y, float* __restrict__ REG)
{
    __shared__ __align__(16) unsigned char smem[16 * APAD * 2];   // 37120 B
    const int bid = blockIdx.x, t = threadIdx.x;
    const int w = t >> 6, lane = t & 63;
    const int col = lane & 15, quad = lane >> 4;
    const f32x4 zero4 = {0.f, 0.f, 0.f, 0.f};

    if (bid < 128) {
        // ---- y role: 16b x 64o tile; B reads now 8 lines/wave-load (K-chunk-major) ----
        half_t (*A)[APAD] = (half_t (*)[APAD])smem;
        const int m0 = (bid >> 1) * 16;
        const int nh = bid & 1;
#pragma unroll
        for (int idx = t; idx < 16 * 144; idx += 256) {
            const int r = idx / 144, c = idx % 144;
            *(half8*)&A[r][c * 8] = *(const half8*)&ws[(m0 + r) * KTOT + c * 8];
        }
        __syncthreads();

        const int o = nh * 64 + w * 16 + col;
        f32x4 acc = zero4;
#pragma unroll 6
        for (int kt = 0; kt < 36; ++kt) {
            const half8 a = *(const half8*)&A[col][kt * 32 + quad * 8];
            const half8 b = *(const half8*)&ws[WC_OFF + ((kt * 4 + quad) * 128 + o) * 8];
            acc = __builtin_amdgcn_mfma_f32_16x16x32_f16(a, b, acc, 0, 0, 0);
        }
#pragma unroll
        for (int r = 0; r < 4; ++r)
            Y[(m0 + quad * 4 + r) * OUTDIM + o] = acc[r] * (1.0f / INDIM);
    } else {
        // ---- REG role: (in, 16-o slice), |spl| over all b ----
        float* SH = (float*)smem;
        const int rb = bid - 128;
        const int in = rb & 127;
        const int o0 = (rb >> 7) * 16;

        // raw W fragment, converted in-kernel
        half8 bfrag = {0, 0, 0, 0, 0, 0, 0, 0};
        if (quad == 0) {
            const int s = (o0 + col) * INDIM + in;
            const float4 w0 = *(const float4*)&W[s * 8];
            const float4 w1 = *(const float4*)&W[s * 8 + 4];
            bfrag = cvt8(w0, w1, 1.0f);
        }
        float r0 = 0.f, r1 = 0.f, r2 = 0.f, r3 = 0.f;
#pragma unroll 4
        for (int bt = w; bt < 64; bt += 4) {   // 4 waves split the 64 b-tiles
            half8 a = {0, 0, 0, 0, 0, 0, 0, 0};
            if (quad == 0)
                a = *(const half8*)&ws[BH2_OFF + in * (BATCH * 8) + (bt * 16 + col) * 8];
            const f32x4 c = __builtin_amdgcn_mfma_f32_16x16x32_f16(a, bfrag, zero4, 0, 0, 0);
            r0 += fabsf(c[0]); r1 += fabsf(c[1]); r2 += fabsf(c[2]); r3 += fabsf(c[3]);
        }
        float sum = (r0 + r1) + (r2 + r3);
        sum += __shfl_xor(sum, 16);
        sum += __shfl_xor(sum, 32);
        if (lane < 16) SH[w * 16 + lane] = sum;
        __syncthreads();
        if (t < 16) {
            const int s = (o0 + t) * INDIM + in;
            const float gg0 = G[s * 6], gg5 = G[s * 6 + 5];
            REG[s] = (SH[t] + SH[16 + t] + SH[32 + t] + SH[48 + t])
                     * (1.0f / BATCH) / (gg5 - gg0 + 1e-5f);
        }
    }
}

extern "C" void kernel_launch(void* const* d_in, const int* in_sizes, int n_in,
                              void* d_out, int out_size, void* d_ws, size_t ws_size,
                              hipStream_t stream) {
    const float* X   = (const float*)d_in[0];
    const float* G   = (const float*)d_in[1];
    const float* W   = (const float*)d_in[2];
    const float* Csp = (const float*)d_in[3];
    const float* Cre = (const float*)d_in[4];
    float* Y   = (float*)d_out;                    // (1024,128) unique-owner stores
    float* REG = (float*)d_out + BATCH * OUTDIM;   // (128,128)  unique-owner stores
    half_t* ws = (half_t*)d_ws;

    k_prep<<<1088, 256, 0, stream>>>(X, G, W, Csp, Cre, ws);
    k_main<<<1152, 256, 0, stream>>>(G, W, ws, Y, REG);
}